// Round 3
// baseline (668.884 us; speedup 1.0000x reference)
//
#include <hip/hip_runtime.h>
#include <stdint.h>

#define HDIM 4096
#define WDIM 4096
#define HWN (HDIM*WDIM)
#define NBIN 512

// ---------------- init: zero binstats, init minmax ----------------
__global__ void init_kernel(float* __restrict__ binstats, int* __restrict__ minmax) {
    int t = threadIdx.x;
    for (int i = t; i < 5 * NBIN; i += 256) binstats[i] = 0.f;
    if (t < 3) { minmax[t] = 0x7F800000; minmax[3 + t] = 0; }  // +inf bits / 0 (all vals >= 0)
}

// ---------------- pass A: per-channel min/max of raw image ----------------
__global__ void __launch_bounds__(256) minmax_kernel(const float* __restrict__ img,
                                                     int* __restrict__ minmax) {
    const int c = blockIdx.y;
    const float4* p = (const float4*)(img + (size_t)c * HWN);
    const int n4 = HWN / 4;
    float mn = 1e30f, mx = -1e30f;
    for (int i = blockIdx.x * 256 + threadIdx.x; i < n4; i += 256 * gridDim.x) {
        float4 v = p[i];
        mn = fminf(mn, fminf(fminf(v.x, v.y), fminf(v.z, v.w)));
        mx = fmaxf(mx, fmaxf(fmaxf(v.x, v.y), fmaxf(v.z, v.w)));
    }
#pragma unroll
    for (int off = 32; off > 0; off >>= 1) {
        mn = fminf(mn, __shfl_down(mn, off));
        mx = fmaxf(mx, __shfl_down(mx, off));
    }
    __shared__ float smn[4], smx[4];
    int lane = threadIdx.x & 63, wid = threadIdx.x >> 6;
    if (lane == 0) { smn[wid] = mn; smx[wid] = mx; }
    __syncthreads();
    if (threadIdx.x == 0) {
        for (int w = 1; w < 4; w++) { mn = fminf(mn, smn[w]); mx = fmaxf(mx, smx[w]); }
        // values are non-negative floats -> int-pattern compare == float compare
        atomicMin(&minmax[c], __float_as_int(mn));
        atomicMax(&minmax[3 + c], __float_as_int(mx));
    }
}

// ---------------- pass B: quantize, write bin map, scatter-sum stats ----------------
__global__ void __launch_bounds__(256) quant_kernel(const float* __restrict__ img,
                                                    const int* __restrict__ minmax,
                                                    uint16_t* __restrict__ linmap,
                                                    float* __restrict__ binstats) {
    __shared__ int qlut[3 * 256];
    __shared__ float s_cnt[NBIN], s_x[NBIN], s_y[NBIN], s_x2[NBIN], s_y2[NBIN];
    for (int i = threadIdx.x; i < NBIN; i += 256) {
        s_cnt[i] = 0.f; s_x[i] = 0.f; s_y[i] = 0.f; s_x2[i] = 0.f; s_y2[i] = 0.f;
    }
    // exact per-integer-lab-value binning LUT: same IEEE f32 division as reference
    for (int i = threadIdx.x; i < 3 * 256; i += 256) {
        int c = i >> 8, t = i & 255;
        float cmn = floorf(__int_as_float(minmax[c]) * 255.f);
        float cmx = floorf(__int_as_float(minmax[3 + c]) * 255.f);
        float step = fmaxf((cmx - cmn) / 8.f, 1e-12f);
        float q = floorf(((float)t - cmn) / step);
        int qi = (int)q;
        qi = qi < 0 ? 0 : (qi > 7 ? 7 : qi);
        qlut[i] = qi;
    }
    __syncthreads();
    const float4* i0 = (const float4*)img;
    const float4* i1 = (const float4*)(img + (size_t)HWN);
    const float4* i2 = (const float4*)(img + (size_t)2 * HWN);
    const int n4 = HWN / 4;
    for (int i = blockIdx.x * 256 + threadIdx.x; i < n4; i += 256 * gridDim.x) {
        float4 a = i0[i], b = i1[i], c = i2[i];
        int p = i * 4;
        float yf = (float)(p >> 12);
        int xb = p & (WDIM - 1);
        float va[4] = {a.x, a.y, a.z, a.w};
        float vb[4] = {b.x, b.y, b.z, b.w};
        float vc[4] = {c.x, c.y, c.z, c.w};
        unsigned short ls[4];
#pragma unroll
        for (int j = 0; j < 4; j++) {
            int l0 = (int)floorf(va[j] * 255.f); l0 = l0 < 0 ? 0 : (l0 > 255 ? 255 : l0);
            int l1 = (int)floorf(vb[j] * 255.f); l1 = l1 < 0 ? 0 : (l1 > 255 ? 255 : l1);
            int l2 = (int)floorf(vc[j] * 255.f); l2 = l2 < 0 ? 0 : (l2 > 255 ? 255 : l2);
            int bin = (qlut[l0] << 6) | (qlut[256 + l1] << 3) | qlut[512 + l2];
            ls[j] = (unsigned short)bin;
            float xf = (float)(xb + j);
            unsafeAtomicAdd(&s_cnt[bin], 1.f);
            unsafeAtomicAdd(&s_x[bin], xf);
            unsafeAtomicAdd(&s_y[bin], yf);
            unsafeAtomicAdd(&s_x2[bin], xf * xf);
            unsafeAtomicAdd(&s_y2[bin], yf * yf);
        }
        ushort4 lv; lv.x = ls[0]; lv.y = ls[1]; lv.z = ls[2]; lv.w = ls[3];
        ((ushort4*)linmap)[i] = lv;
    }
    __syncthreads();
    for (int i = threadIdx.x; i < NBIN; i += 256) {
        unsafeAtomicAdd(&binstats[i], s_cnt[i]);
        unsafeAtomicAdd(&binstats[NBIN + i], s_x[i]);
        unsafeAtomicAdd(&binstats[2 * NBIN + i], s_y[i]);
        unsafeAtomicAdd(&binstats[3 * NBIN + i], s_x2[i]);
        unsafeAtomicAdd(&binstats[4 * NBIN + i], s_y2[i]);
    }
}

// ---------------- pass C: 512-bin color-space math (single block) ----------------
__global__ void __launch_bounds__(512) binproc_kernel(const float* __restrict__ binstats,
                                                      const int* __restrict__ minmax,
                                                      float* __restrict__ norm_sal) {
    __shared__ float sh[NBIN], sx[NBIN], sy[NBIN], sx2[NBIN], sy2[NBIN];
    __shared__ float salm[NBIN], maskf[NBIN];
    __shared__ float e0[8], e1[8], e2[8];
    __shared__ float rmn[8], rmx[8];
    const int b = threadIdx.x;
    sh[b]  = binstats[b];
    sx[b]  = binstats[NBIN + b];
    sy[b]  = binstats[2 * NBIN + b];
    sx2[b] = binstats[3 * NBIN + b];
    sy2[b] = binstats[4 * NBIN + b];
    if (b < 24) {
        int c = b >> 3, k = b & 7;
        float cmn = floorf(__int_as_float(minmax[c]) * 255.f);
        float cmx = floorf(__int_as_float(minmax[3 + c]) * 255.f);
        float step = fmaxf((cmx - cmn) / 8.f, 1e-12f);
        float e = cmn + (float)k * step;
        if (c == 0) e0[k] = e; else if (c == 1) e1[k] = e; else e2[k] = e;
    }
    __syncthreads();
    const float c0 = e0[b >> 6], c1 = e1[(b >> 3) & 7], c2 = e2[b & 7];
    float contrast = 0.f, en = 0.f, ex = 0.f, ey = 0.f, ex2 = 0.f, ey2 = 0.f;
    for (int j = 0; j < NBIN; j++) {
        float d0 = c0 - e0[j >> 6], d1 = c1 - e1[(j >> 3) & 7], d2c = c2 - e2[j & 7];
        float d2 = d0 * d0 + d1 * d1 + d2c * d2c;
        float D = sqrtf(d2);
        float E = __expf(-d2 * (1.f / 512.f));
        float h = sh[j];
        contrast += D * h; en += E * h;
        ex += E * sx[j]; ey += E * sy[j]; ex2 += E * sx2[j]; ey2 += E * sy2[j];
    }
    float norm = fmaxf(en, 1e-8f);
    float mx = ex / norm, my = ey / norm, mx2 = ex2 / norm, my2 = ey2 / norm;
    float vx = fmaxf(mx2 - mx * mx, 0.f), vy = fmaxf(my2 - my * my, 0.f);
    float g0 = sqrtf(12.f * vx) / 4096.f;
    float g1 = sqrtf(12.f * vy) / 4096.f;
    float g2 = (mx - 2048.f) / 4096.f;
    float g3 = (my - 2048.f) / 4096.f;
    const float CI[4][4] = {{43.3777f, 1.7633f, -0.4059f, 1.0997f},
                            {1.7633f, 40.7221f, -0.0165f, 0.0447f},
                            {-0.4059f, -0.0165f, 87.0455f, -3.2744f},
                            {1.0997f, 0.0447f, -3.2744f, 125.1503f}};
    float xc[4] = {g0 - 0.5555f, g1 - 0.6449f, g2 - 0.0002f, g3 - 0.0063f};
    float maha = 0.f;
#pragma unroll
    for (int ii = 0; ii < 4; ii++)
#pragma unroll
        for (int jj = 0; jj < 4; jj++) maha += xc[ii] * CI[ii][jj] * xc[jj];
    float sp = __expf(-0.5f * maha);
    float sal = contrast * sp;
    float mf = sh[b] > 0.f ? 1.f : 0.f;
    salm[b] = sal * mf;
    maskf[b] = mf;
    __syncthreads();
    float num = 0.f, den = 0.f;
    for (int j = 0; j < NBIN; j++) {
        float d0 = c0 - e0[j >> 6], d1 = c1 - e1[(j >> 3) & 7], d2c = c2 - e2[j & 7];
        float d2 = d0 * d0 + d1 * d1 + d2c * d2c;
        float E = __expf(-d2 * (1.f / 512.f));
        num += E * salm[j]; den += E * maskf[j];
    }
    float smoothed = num / fmaxf(den, 1e-8f);
    float vmn = mf > 0.f ? smoothed : INFINITY;
    float vmx = mf > 0.f ? smoothed : -INFINITY;
#pragma unroll
    for (int off = 32; off > 0; off >>= 1) {
        vmn = fminf(vmn, __shfl_down(vmn, off));
        vmx = fmaxf(vmx, __shfl_down(vmx, off));
    }
    int lane = b & 63, wid = b >> 6;
    if (lane == 0) { rmn[wid] = vmn; rmx[wid] = vmx; }
    __syncthreads();
    if (b == 0) {
        float a = rmn[0], z = rmx[0];
        for (int w = 1; w < 8; w++) { a = fminf(a, rmn[w]); z = fmaxf(z, rmx[w]); }
        rmn[0] = a; rmx[0] = z;
    }
    __syncthreads();
    float mnv = rmn[0], mxv = rmx[0];
    float ns = (mxv > mnv) ? 255.f * (smoothed - mnv) / fmaxf(mxv - mnv, 1e-30f) : 0.f;
    norm_sal[b] = ns;
}

// ---------------- pass D: gather + horizontal 10-tap sum ----------------
#define RPB 4
__global__ void __launch_bounds__(256) hblur_kernel(const uint16_t* __restrict__ linmap,
                                                    const float* __restrict__ norm_sal,
                                                    float* __restrict__ temp) {
    __shared__ float lut[NBIN];
    __shared__ float sv[256 + 9];
    for (int i = threadIdx.x; i < NBIN; i += 256) lut[i] = norm_sal[i];
    const int x0 = blockIdx.x * 256;
    for (int r = 0; r < RPB; r++) {
        const int y = blockIdx.y * RPB + r;
        __syncthreads();
        for (int t = threadIdx.x; t < 265; t += 256) {
            int v = x0 - 5 + t;
            v = v < 0 ? -v : (v >= WDIM ? 2 * WDIM - 2 - v : v);  // reflect-101
            sv[t] = lut[linmap[(size_t)y * WDIM + v]];
        }
        __syncthreads();
        float s = 0.f;
#pragma unroll
        for (int k = 0; k < 10; k++) s += sv[threadIdx.x + k];
        temp[(size_t)y * WDIM + x0 + threadIdx.x] = s;
    }
}

// ---------------- pass E: vertical 10-tap sliding sum + scale ----------------
#define YB 64
__global__ void __launch_bounds__(256) vblur_kernel(const float* __restrict__ temp,
                                                    float* __restrict__ out) {
    const int x = blockIdx.x * 256 + threadIdx.x;
    const int y0 = blockIdx.y * YB;
    float s = 0.f;
#pragma unroll
    for (int u = y0 - 5; u < y0 + 5; u++) {
        int ur = u < 0 ? -u : (u >= HDIM ? 2 * HDIM - 2 - u : u);
        s += temp[(size_t)ur * WDIM + x];
    }
    for (int yy = y0; yy < y0 + YB; yy++) {
        out[(size_t)yy * WDIM + x] = s * (1.f / 100.f) * (1.f / 255.f);
        int ua = yy + 5, ub = yy - 5;
        int ura = ua >= HDIM ? 2 * HDIM - 2 - ua : ua;
        int urb = ub < 0 ? -ub : ub;
        s += temp[(size_t)ura * WDIM + x] - temp[(size_t)urb * WDIM + x];
    }
}

extern "C" void kernel_launch(void* const* d_in, const int* in_sizes, int n_in,
                              void* d_out, int out_size, void* d_ws, size_t ws_size,
                              hipStream_t stream) {
    const float* img = (const float*)d_in[0];
    float* out = (float*)d_out;
    char* ws = (char*)d_ws;
    // ws layout: linmap (2*HWN) | temp (4*HWN) | binstats (5*512*4) | minmax (24) | norm_sal (2048)
    uint16_t* linmap = (uint16_t*)ws;
    float* temp = (float*)(ws + (size_t)2 * HWN);
    float* binstats = (float*)(ws + (size_t)6 * HWN);
    int* minmax = (int*)(ws + (size_t)6 * HWN + 10240);
    float* norm_sal = (float*)(ws + (size_t)6 * HWN + 10240 + 256);

    init_kernel<<<1, 256, 0, stream>>>(binstats, minmax);
    minmax_kernel<<<dim3(512, 3), 256, 0, stream>>>(img, minmax);
    quant_kernel<<<1024, 256, 0, stream>>>(img, minmax, linmap, binstats);
    binproc_kernel<<<1, 512, 0, stream>>>(binstats, minmax, norm_sal);
    hblur_kernel<<<dim3(WDIM / 256, HDIM / RPB), 256, 0, stream>>>(linmap, norm_sal, temp);
    vblur_kernel<<<dim3(WDIM / 256, HDIM / YB), 256, 0, stream>>>(temp, out);
}

// Round 5
// 294.321 us; speedup vs baseline: 2.2726x; 2.2726x over previous
//
#include <hip/hip_runtime.h>
#include <stdint.h>

#define HDIM 4096
#define WDIM 4096
#define HWN (HDIM*WDIM)
#define NBIN 512

typedef unsigned long long u64;

// ---------------- init: zero integer binstats, init minmax ----------------
__global__ void init_kernel(u64* __restrict__ g64, int* __restrict__ minmax) {
    int t = threadIdx.x;
    for (int i = t; i < 5 * NBIN; i += 256) g64[i] = 0ull;
    if (t < 3) { minmax[t] = 0x7F800000; minmax[3 + t] = 0; }  // +inf bits / 0 (all vals >= 0)
}

// ---------------- pass A: per-channel min/max of raw image ----------------
__global__ void __launch_bounds__(256) minmax_kernel(const float* __restrict__ img,
                                                     int* __restrict__ minmax) {
    const int c = blockIdx.y;
    const float4* p = (const float4*)(img + (size_t)c * HWN);
    const int n4 = HWN / 4;
    float mn = 1e30f, mx = -1e30f;
    for (int i = blockIdx.x * 256 + threadIdx.x; i < n4; i += 256 * gridDim.x) {
        float4 v = p[i];
        mn = fminf(mn, fminf(fminf(v.x, v.y), fminf(v.z, v.w)));
        mx = fmaxf(mx, fmaxf(fmaxf(v.x, v.y), fmaxf(v.z, v.w)));
    }
#pragma unroll
    for (int off = 32; off > 0; off >>= 1) {
        mn = fminf(mn, __shfl_down(mn, off));
        mx = fmaxf(mx, __shfl_down(mx, off));
    }
    __shared__ float smn[4], smx[4];
    int lane = threadIdx.x & 63, wid = threadIdx.x >> 6;
    if (lane == 0) { smn[wid] = mn; smx[wid] = mx; }
    __syncthreads();
    if (threadIdx.x == 0) {
        for (int w = 1; w < 4; w++) { mn = fminf(mn, smn[w]); mx = fmaxf(mx, smx[w]); }
        // values are non-negative floats -> int-pattern compare == float compare
        atomicMin(&minmax[c], __float_as_int(mn));
        atomicMax(&minmax[3 + c], __float_as_int(mx));
    }
}

// ---------------- pass B: quantize, write bin map, scatter-sum stats ----------------
// Packed integer LDS accumulation (2 ds_add_u64 per pixel instead of 5 ds_add_f32):
//   A = cnt<<52 | sum_x<<26 | sum_y      (per-block per-bin: cnt<~70, sum_x<~287K << 2^26)
//   B = sum_x2<<32 | sum_y2              (sum_x2 <~ 1.2e9 << 2^32)
__global__ void __launch_bounds__(256) quant_kernel(const float* __restrict__ img,
                                                    const int* __restrict__ minmax,
                                                    uint16_t* __restrict__ linmap,
                                                    u64* __restrict__ g64) {
    __shared__ int qlut[3 * 256];
    __shared__ u64 sA[NBIN], sB[NBIN];
    for (int i = threadIdx.x; i < NBIN; i += 256) { sA[i] = 0ull; sB[i] = 0ull; }
    // exact per-integer-lab-value binning LUT: same IEEE f32 division as reference
    for (int i = threadIdx.x; i < 3 * 256; i += 256) {
        int c = i >> 8, t = i & 255;
        float cmn = floorf(__int_as_float(minmax[c]) * 255.f);
        float cmx = floorf(__int_as_float(minmax[3 + c]) * 255.f);
        float step = fmaxf((cmx - cmn) / 8.f, 1e-12f);
        float q = floorf(((float)t - cmn) / step);
        int qi = (int)q;
        qi = qi < 0 ? 0 : (qi > 7 ? 7 : qi);
        qlut[i] = qi;
    }
    __syncthreads();
    const float4* i0 = (const float4*)img;
    const float4* i1 = (const float4*)(img + (size_t)HWN);
    const float4* i2 = (const float4*)(img + (size_t)2 * HWN);
    const int n4 = HWN / 4;
    for (int i = blockIdx.x * 256 + threadIdx.x; i < n4; i += 256 * gridDim.x) {
        float4 a = i0[i], b = i1[i], c = i2[i];
        int p = i * 4;
        int y = p >> 12;
        int xb = p & (WDIM - 1);
        u64 Abase = (1ull << 52) | (u64)(unsigned)y;
        u64 Bbase = (u64)(unsigned)(y * y);
        float va[4] = {a.x, a.y, a.z, a.w};
        float vb[4] = {b.x, b.y, b.z, b.w};
        float vc[4] = {c.x, c.y, c.z, c.w};
        unsigned short ls[4];
#pragma unroll
        for (int j = 0; j < 4; j++) {
            int l0 = (int)floorf(va[j] * 255.f); l0 = l0 < 0 ? 0 : (l0 > 255 ? 255 : l0);
            int l1 = (int)floorf(vb[j] * 255.f); l1 = l1 < 0 ? 0 : (l1 > 255 ? 255 : l1);
            int l2 = (int)floorf(vc[j] * 255.f); l2 = l2 < 0 ? 0 : (l2 > 255 ? 255 : l2);
            int bin = (qlut[l0] << 6) | (qlut[256 + l1] << 3) | qlut[512 + l2];
            ls[j] = (unsigned short)bin;
            int x = xb + j;
            atomicAdd(&sA[bin], Abase | ((u64)(unsigned)x << 26));
            atomicAdd(&sB[bin], ((u64)(unsigned)(x * x) << 32) | Bbase);
        }
        ushort4 lv; lv.x = ls[0]; lv.y = ls[1]; lv.z = ls[2]; lv.w = ls[3];
        ((ushort4*)linmap)[i] = lv;
    }
    __syncthreads();
    for (int i = threadIdx.x; i < NBIN; i += 256) {
        u64 A = sA[i];
        if (A) {
            u64 B = sB[i];
            atomicAdd(&g64[i],            A >> 52);                    // count
            atomicAdd(&g64[NBIN + i],     (A >> 26) & 0x3FFFFFFull);   // sum x
            atomicAdd(&g64[2 * NBIN + i], A & 0x3FFFFFFull);           // sum y
            atomicAdd(&g64[3 * NBIN + i], B >> 32);                    // sum x^2
            atomicAdd(&g64[4 * NBIN + i], B & 0xFFFFFFFFull);          // sum y^2
        }
    }
}

// ---------------- pass C: 512-bin color-space math (single block) ----------------
__global__ void __launch_bounds__(512) binproc_kernel(const u64* __restrict__ g64,
                                                      const int* __restrict__ minmax,
                                                      float* __restrict__ norm_sal) {
    __shared__ float sh[NBIN], sx[NBIN], sy[NBIN], sx2[NBIN], sy2[NBIN];
    __shared__ float salm[NBIN], maskf[NBIN];
    __shared__ float e0[8], e1[8], e2[8];
    __shared__ float rmn[8], rmx[8];
    const int b = threadIdx.x;
    u64 cnt = g64[b];
    sh[b]  = (float)cnt;
    sx[b]  = (float)g64[NBIN + b];
    sy[b]  = (float)g64[2 * NBIN + b];
    sx2[b] = (float)g64[3 * NBIN + b];
    sy2[b] = (float)g64[4 * NBIN + b];
    if (b < 24) {
        int c = b >> 3, k = b & 7;
        float cmn = floorf(__int_as_float(minmax[c]) * 255.f);
        float cmx = floorf(__int_as_float(minmax[3 + c]) * 255.f);
        float step = fmaxf((cmx - cmn) / 8.f, 1e-12f);
        float e = cmn + (float)k * step;
        if (c == 0) e0[k] = e; else if (c == 1) e1[k] = e; else e2[k] = e;
    }
    __syncthreads();
    const float c0 = e0[b >> 6], c1 = e1[(b >> 3) & 7], c2 = e2[b & 7];
    float contrast = 0.f, en = 0.f, ex = 0.f, ey = 0.f, ex2 = 0.f, ey2 = 0.f;
    for (int j = 0; j < NBIN; j++) {
        float d0 = c0 - e0[j >> 6], d1 = c1 - e1[(j >> 3) & 7], d2c = c2 - e2[j & 7];
        float d2 = d0 * d0 + d1 * d1 + d2c * d2c;
        float D = sqrtf(d2);
        float E = __expf(-d2 * (1.f / 512.f));
        float h = sh[j];
        contrast += D * h; en += E * h;
        ex += E * sx[j]; ey += E * sy[j]; ex2 += E * sx2[j]; ey2 += E * sy2[j];
    }
    float norm = fmaxf(en, 1e-8f);
    float mx = ex / norm, my = ey / norm, mx2 = ex2 / norm, my2 = ey2 / norm;
    float vx = fmaxf(mx2 - mx * mx, 0.f), vy = fmaxf(my2 - my * my, 0.f);
    float g0 = sqrtf(12.f * vx) / 4096.f;
    float g1 = sqrtf(12.f * vy) / 4096.f;
    float g2 = (mx - 2048.f) / 4096.f;
    float g3 = (my - 2048.f) / 4096.f;
    const float CI[4][4] = {{43.3777f, 1.7633f, -0.4059f, 1.0997f},
                            {1.7633f, 40.7221f, -0.0165f, 0.0447f},
                            {-0.4059f, -0.0165f, 87.0455f, -3.2744f},
                            {1.0997f, 0.0447f, -3.2744f, 125.1503f}};
    float xc[4] = {g0 - 0.5555f, g1 - 0.6449f, g2 - 0.0002f, g3 - 0.0063f};
    float maha = 0.f;
#pragma unroll
    for (int ii = 0; ii < 4; ii++)
#pragma unroll
        for (int jj = 0; jj < 4; jj++) maha += xc[ii] * CI[ii][jj] * xc[jj];
    float sp = __expf(-0.5f * maha);
    float sal = contrast * sp;
    float mf = cnt > 0 ? 1.f : 0.f;
    salm[b] = sal * mf;
    maskf[b] = mf;
    __syncthreads();
    float num = 0.f, den = 0.f;
    for (int j = 0; j < NBIN; j++) {
        float d0 = c0 - e0[j >> 6], d1 = c1 - e1[(j >> 3) & 7], d2c = c2 - e2[j & 7];
        float d2 = d0 * d0 + d1 * d1 + d2c * d2c;
        float E = __expf(-d2 * (1.f / 512.f));
        num += E * salm[j]; den += E * maskf[j];
    }
    float smoothed = num / fmaxf(den, 1e-8f);
    float vmn = mf > 0.f ? smoothed : INFINITY;
    float vmx = mf > 0.f ? smoothed : -INFINITY;
#pragma unroll
    for (int off = 32; off > 0; off >>= 1) {
        vmn = fminf(vmn, __shfl_down(vmn, off));
        vmx = fmaxf(vmx, __shfl_down(vmx, off));
    }
    int lane = b & 63, wid = b >> 6;
    if (lane == 0) { rmn[wid] = vmn; rmx[wid] = vmx; }
    __syncthreads();
    if (b == 0) {
        float a = rmn[0], z = rmx[0];
        for (int w = 1; w < 8; w++) { a = fminf(a, rmn[w]); z = fmaxf(z, rmx[w]); }
        rmn[0] = a; rmx[0] = z;
    }
    __syncthreads();
    float mnv = rmn[0], mxv = rmx[0];
    float ns = (mxv > mnv) ? 255.f * (smoothed - mnv) / fmaxf(mxv - mnv, 1e-30f) : 0.f;
    norm_sal[b] = ns;
}

// ---------------- pass D: gather + horizontal 10-tap sum ----------------
#define RPB 4
__global__ void __launch_bounds__(256) hblur_kernel(const uint16_t* __restrict__ linmap,
                                                    const float* __restrict__ norm_sal,
                                                    float* __restrict__ temp) {
    __shared__ float lut[NBIN];
    __shared__ float sv[256 + 9];
    for (int i = threadIdx.x; i < NBIN; i += 256) lut[i] = norm_sal[i];
    const int x0 = blockIdx.x * 256;
    for (int r = 0; r < RPB; r++) {
        const int y = blockIdx.y * RPB + r;
        __syncthreads();
        for (int t = threadIdx.x; t < 265; t += 256) {
            int v = x0 - 5 + t;
            v = v < 0 ? -v : (v >= WDIM ? 2 * WDIM - 2 - v : v);  // reflect-101
            sv[t] = lut[linmap[(size_t)y * WDIM + v]];
        }
        __syncthreads();
        float s = 0.f;
#pragma unroll
        for (int k = 0; k < 10; k++) s += sv[threadIdx.x + k];
        temp[(size_t)y * WDIM + x0 + threadIdx.x] = s;
    }
}

// ---------------- pass E: vertical 10-tap sliding sum + scale ----------------
#define YB 64
__global__ void __launch_bounds__(256) vblur_kernel(const float* __restrict__ temp,
                                                    float* __restrict__ out) {
    const int x = blockIdx.x * 256 + threadIdx.x;
    const int y0 = blockIdx.y * YB;
    float s = 0.f;
#pragma unroll
    for (int u = y0 - 5; u < y0 + 5; u++) {
        int ur = u < 0 ? -u : (u >= HDIM ? 2 * HDIM - 2 - u : u);
        s += temp[(size_t)ur * WDIM + x];
    }
    for (int yy = y0; yy < y0 + YB; yy++) {
        out[(size_t)yy * WDIM + x] = s * (1.f / 100.f) * (1.f / 255.f);
        int ua = yy + 5, ub = yy - 5;
        int ura = ua >= HDIM ? 2 * HDIM - 2 - ua : ua;
        int urb = ub < 0 ? -ub : ub;
        s += temp[(size_t)ura * WDIM + x] - temp[(size_t)urb * WDIM + x];
    }
}

extern "C" void kernel_launch(void* const* d_in, const int* in_sizes, int n_in,
                              void* d_out, int out_size, void* d_ws, size_t ws_size,
                              hipStream_t stream) {
    const float* img = (const float*)d_in[0];
    float* out = (float*)d_out;
    char* ws = (char*)d_ws;
    // ws layout: linmap (2*HWN) | temp (4*HWN) | g64 (5*512*8) | minmax (24) | norm_sal (2048)
    uint16_t* linmap = (uint16_t*)ws;
    float* temp = (float*)(ws + (size_t)2 * HWN);
    u64* g64 = (u64*)(ws + (size_t)6 * HWN);
    int* minmax = (int*)(ws + (size_t)6 * HWN + 20480);
    float* norm_sal = (float*)(ws + (size_t)6 * HWN + 20480 + 256);

    init_kernel<<<1, 256, 0, stream>>>(g64, minmax);
    minmax_kernel<<<dim3(512, 3), 256, 0, stream>>>(img, minmax);
    quant_kernel<<<1024, 256, 0, stream>>>(img, minmax, linmap, g64);
    binproc_kernel<<<1, 512, 0, stream>>>(g64, minmax, norm_sal);
    hblur_kernel<<<dim3(WDIM / 256, HDIM / RPB), 256, 0, stream>>>(linmap, norm_sal, temp);
    vblur_kernel<<<dim3(WDIM / 256, HDIM / YB), 256, 0, stream>>>(temp, out);
}

// Round 6
// 275.284 us; speedup vs baseline: 2.4298x; 1.0692x over previous
//
#include <hip/hip_runtime.h>
#include <stdint.h>

#define HDIM 4096
#define WDIM 4096
#define HWN (HDIM*WDIM)
#define NBIN 512

typedef unsigned long long u64;

// ---------------- init: zero integer binstats, init int minmax ----------------
__global__ void init_kernel(u64* __restrict__ g64, int* __restrict__ minmax) {
    int t = threadIdx.x;
    for (int i = t; i < 5 * NBIN; i += 256) g64[i] = 0ull;
    if (t < 3) { minmax[t] = 255; minmax[3 + t] = 0; }
}

// ---------------- pass A: img f32 -> lab byte planes + integer min/max ----------------
// lab = floor(img*255) clamped to [0,255]; floor is monotone so int min/max of bytes
// equals floor(min/max of floats) -> binning LUT stays bit-exact vs reference.
__global__ void __launch_bounds__(256) lab_kernel(const float* __restrict__ img,
                                                  uint8_t* __restrict__ lab,
                                                  int* __restrict__ minmax) {
    const int n4 = HWN / 4;
    int mn0 = 255, mn1 = 255, mn2 = 255, mx0 = 0, mx1 = 0, mx2 = 0;
    for (int i = blockIdx.x * 256 + threadIdx.x; i < n4; i += 256 * gridDim.x) {
#pragma unroll
        for (int c = 0; c < 3; c++) {
            float4 v = ((const float4*)(img + (size_t)c * HWN))[i];
            int b0 = (int)floorf(v.x * 255.f); b0 = b0 < 0 ? 0 : (b0 > 255 ? 255 : b0);
            int b1 = (int)floorf(v.y * 255.f); b1 = b1 < 0 ? 0 : (b1 > 255 ? 255 : b1);
            int b2 = (int)floorf(v.z * 255.f); b2 = b2 < 0 ? 0 : (b2 > 255 ? 255 : b2);
            int b3 = (int)floorf(v.w * 255.f); b3 = b3 < 0 ? 0 : (b3 > 255 ? 255 : b3);
            ((unsigned*)(lab + (size_t)c * HWN))[i] =
                (unsigned)b0 | ((unsigned)b1 << 8) | ((unsigned)b2 << 16) | ((unsigned)b3 << 24);
            int lmn = min(min(b0, b1), min(b2, b3));
            int lmx = max(max(b0, b1), max(b2, b3));
            if (c == 0) { mn0 = min(mn0, lmn); mx0 = max(mx0, lmx); }
            else if (c == 1) { mn1 = min(mn1, lmn); mx1 = max(mx1, lmx); }
            else { mn2 = min(mn2, lmn); mx2 = max(mx2, lmx); }
        }
    }
#pragma unroll
    for (int off = 32; off > 0; off >>= 1) {
        mn0 = min(mn0, __shfl_down(mn0, off)); mx0 = max(mx0, __shfl_down(mx0, off));
        mn1 = min(mn1, __shfl_down(mn1, off)); mx1 = max(mx1, __shfl_down(mx1, off));
        mn2 = min(mn2, __shfl_down(mn2, off)); mx2 = max(mx2, __shfl_down(mx2, off));
    }
    __shared__ int smn[3][4], smx[3][4];
    int lane = threadIdx.x & 63, wid = threadIdx.x >> 6;
    if (lane == 0) {
        smn[0][wid] = mn0; smx[0][wid] = mx0;
        smn[1][wid] = mn1; smx[1][wid] = mx1;
        smn[2][wid] = mn2; smx[2][wid] = mx2;
    }
    __syncthreads();
    if (threadIdx.x < 3) {
        int c = threadIdx.x;
        int a = min(min(smn[c][0], smn[c][1]), min(smn[c][2], smn[c][3]));
        int z = max(max(smx[c][0], smx[c][1]), max(smx[c][2], smx[c][3]));
        atomicMin(&minmax[c], a);
        atomicMax(&minmax[3 + c], z);
    }
}

// ---------------- pass B: quantize bytes, write bin map, packed-u64 scatter stats ----------------
//   A = cnt<<52 | sum_x<<26 | sum_y ; B = sum_x2<<32 | sum_y2 (per-block fields have headroom)
__global__ void __launch_bounds__(256) quant_kernel(const uint8_t* __restrict__ lab,
                                                    const int* __restrict__ minmax,
                                                    uint16_t* __restrict__ linmap,
                                                    u64* __restrict__ g64) {
    __shared__ uint8_t qlut[3 * 256];
    __shared__ u64 sA[NBIN], sB[NBIN];
    for (int i = threadIdx.x; i < NBIN; i += 256) { sA[i] = 0ull; sB[i] = 0ull; }
    // exact per-integer-lab-value binning LUT: same IEEE f32 division as reference
    for (int i = threadIdx.x; i < 3 * 256; i += 256) {
        int c = i >> 8, t = i & 255;
        float cmn = (float)minmax[c];
        float cmx = (float)minmax[3 + c];
        float step = fmaxf((cmx - cmn) / 8.f, 1e-12f);
        float q = floorf(((float)t - cmn) / step);
        int qi = (int)q;
        qi = qi < 0 ? 0 : (qi > 7 ? 7 : qi);
        qlut[i] = (uint8_t)qi;
    }
    __syncthreads();
    const uint4* p0 = (const uint4*)lab;
    const uint4* p1 = (const uint4*)(lab + (size_t)HWN);
    const uint4* p2 = (const uint4*)(lab + (size_t)2 * HWN);
    const int n16 = HWN / 16;
    for (int i = blockIdx.x * 256 + threadIdx.x; i < n16; i += 256 * gridDim.x) {
        uint4 A = p0[i], B = p1[i], C = p2[i];
        unsigned wa[4] = {A.x, A.y, A.z, A.w};
        unsigned wb[4] = {B.x, B.y, B.z, B.w};
        unsigned wc[4] = {C.x, C.y, C.z, C.w};
        int p = i * 16;
        int y = p >> 12;
        int xb = p & (WDIM - 1);
        u64 Abase = (1ull << 52) | (u64)(unsigned)y;
        u64 Bbase = (u64)(unsigned)(y * y);
        unsigned short bins[16];
#pragma unroll
        for (int w = 0; w < 4; w++) {
#pragma unroll
            for (int k = 0; k < 4; k++) {
                int l0 = (wa[w] >> (8 * k)) & 255;
                int l1 = (wb[w] >> (8 * k)) & 255;
                int l2 = (wc[w] >> (8 * k)) & 255;
                int bin = (qlut[l0] << 6) | (qlut[256 + l1] << 3) | qlut[512 + l2];
                bins[w * 4 + k] = (unsigned short)bin;
                int x = xb + w * 4 + k;
                atomicAdd(&sA[bin], Abase | ((u64)(unsigned)x << 26));
                atomicAdd(&sB[bin], ((u64)(unsigned)(x * x) << 32) | Bbase);
            }
        }
        uint4 o0, o1;
        o0.x = (unsigned)bins[0] | ((unsigned)bins[1] << 16);
        o0.y = (unsigned)bins[2] | ((unsigned)bins[3] << 16);
        o0.z = (unsigned)bins[4] | ((unsigned)bins[5] << 16);
        o0.w = (unsigned)bins[6] | ((unsigned)bins[7] << 16);
        o1.x = (unsigned)bins[8] | ((unsigned)bins[9] << 16);
        o1.y = (unsigned)bins[10] | ((unsigned)bins[11] << 16);
        o1.z = (unsigned)bins[12] | ((unsigned)bins[13] << 16);
        o1.w = (unsigned)bins[14] | ((unsigned)bins[15] << 16);
        ((uint4*)linmap)[i * 2] = o0;
        ((uint4*)linmap)[i * 2 + 1] = o1;
    }
    __syncthreads();
    for (int i = threadIdx.x; i < NBIN; i += 256) {
        u64 A = sA[i];
        if (A) {
            u64 B = sB[i];
            atomicAdd(&g64[i],            A >> 52);
            atomicAdd(&g64[NBIN + i],     (A >> 26) & 0x3FFFFFFull);
            atomicAdd(&g64[2 * NBIN + i], A & 0x3FFFFFFull);
            atomicAdd(&g64[3 * NBIN + i], B >> 32);
            atomicAdd(&g64[4 * NBIN + i], B & 0xFFFFFFFFull);
        }
    }
}

// ---------------- pass C: 512-bin color-space math (single block) ----------------
__global__ void __launch_bounds__(512) binproc_kernel(const u64* __restrict__ g64,
                                                      const int* __restrict__ minmax,
                                                      float* __restrict__ norm_sal) {
    __shared__ float sh[NBIN], sx[NBIN], sy[NBIN], sx2[NBIN], sy2[NBIN];
    __shared__ float salm[NBIN], maskf[NBIN];
    __shared__ float e0[8], e1[8], e2[8];
    __shared__ float rmn[8], rmx[8];
    const int b = threadIdx.x;
    u64 cnt = g64[b];
    sh[b]  = (float)cnt;
    sx[b]  = (float)g64[NBIN + b];
    sy[b]  = (float)g64[2 * NBIN + b];
    sx2[b] = (float)g64[3 * NBIN + b];
    sy2[b] = (float)g64[4 * NBIN + b];
    if (b < 24) {
        int c = b >> 3, k = b & 7;
        float cmn = (float)minmax[c];
        float cmx = (float)minmax[3 + c];
        float step = fmaxf((cmx - cmn) / 8.f, 1e-12f);
        float e = cmn + (float)k * step;
        if (c == 0) e0[k] = e; else if (c == 1) e1[k] = e; else e2[k] = e;
    }
    __syncthreads();
    const float c0 = e0[b >> 6], c1 = e1[(b >> 3) & 7], c2 = e2[b & 7];
    float contrast = 0.f, en = 0.f, ex = 0.f, ey = 0.f, ex2 = 0.f, ey2 = 0.f;
    for (int j = 0; j < NBIN; j++) {
        float d0 = c0 - e0[j >> 6], d1 = c1 - e1[(j >> 3) & 7], d2c = c2 - e2[j & 7];
        float d2 = d0 * d0 + d1 * d1 + d2c * d2c;
        float D = sqrtf(d2);
        float E = __expf(-d2 * (1.f / 512.f));
        float h = sh[j];
        contrast += D * h; en += E * h;
        ex += E * sx[j]; ey += E * sy[j]; ex2 += E * sx2[j]; ey2 += E * sy2[j];
    }
    float norm = fmaxf(en, 1e-8f);
    float mx = ex / norm, my = ey / norm, mx2 = ex2 / norm, my2 = ey2 / norm;
    float vx = fmaxf(mx2 - mx * mx, 0.f), vy = fmaxf(my2 - my * my, 0.f);
    float g0 = sqrtf(12.f * vx) / 4096.f;
    float g1 = sqrtf(12.f * vy) / 4096.f;
    float g2 = (mx - 2048.f) / 4096.f;
    float g3 = (my - 2048.f) / 4096.f;
    const float CI[4][4] = {{43.3777f, 1.7633f, -0.4059f, 1.0997f},
                            {1.7633f, 40.7221f, -0.0165f, 0.0447f},
                            {-0.4059f, -0.0165f, 87.0455f, -3.2744f},
                            {1.0997f, 0.0447f, -3.2744f, 125.1503f}};
    float xc[4] = {g0 - 0.5555f, g1 - 0.6449f, g2 - 0.0002f, g3 - 0.0063f};
    float maha = 0.f;
#pragma unroll
    for (int ii = 0; ii < 4; ii++)
#pragma unroll
        for (int jj = 0; jj < 4; jj++) maha += xc[ii] * CI[ii][jj] * xc[jj];
    float sp = __expf(-0.5f * maha);
    float sal = contrast * sp;
    float mf = cnt > 0 ? 1.f : 0.f;
    salm[b] = sal * mf;
    maskf[b] = mf;
    __syncthreads();
    float num = 0.f, den = 0.f;
    for (int j = 0; j < NBIN; j++) {
        float d0 = c0 - e0[j >> 6], d1 = c1 - e1[(j >> 3) & 7], d2c = c2 - e2[j & 7];
        float d2 = d0 * d0 + d1 * d1 + d2c * d2c;
        float E = __expf(-d2 * (1.f / 512.f));
        num += E * salm[j]; den += E * maskf[j];
    }
    float smoothed = num / fmaxf(den, 1e-8f);
    float vmn = mf > 0.f ? smoothed : INFINITY;
    float vmx = mf > 0.f ? smoothed : -INFINITY;
#pragma unroll
    for (int off = 32; off > 0; off >>= 1) {
        vmn = fminf(vmn, __shfl_down(vmn, off));
        vmx = fmaxf(vmx, __shfl_down(vmx, off));
    }
    int lane = b & 63, wid = b >> 6;
    if (lane == 0) { rmn[wid] = vmn; rmx[wid] = vmx; }
    __syncthreads();
    if (b == 0) {
        float a = rmn[0], z = rmx[0];
        for (int w = 1; w < 8; w++) { a = fminf(a, rmn[w]); z = fmaxf(z, rmx[w]); }
        rmn[0] = a; rmx[0] = z;
    }
    __syncthreads();
    float mnv = rmn[0], mxv = rmx[0];
    float ns = (mxv > mnv) ? 255.f * (smoothed - mnv) / fmaxf(mxv - mnv, 1e-30f) : 0.f;
    norm_sal[b] = ns;
}

// ---------------- pass D: gather + horizontal 10-tap sum (fp16 temp) ----------------
#define RPB 4
__global__ void __launch_bounds__(256) hblur_kernel(const uint16_t* __restrict__ linmap,
                                                    const float* __restrict__ norm_sal,
                                                    _Float16* __restrict__ temp) {
    __shared__ float lut[NBIN];
    __shared__ float sv[256 + 9];
    for (int i = threadIdx.x; i < NBIN; i += 256) lut[i] = norm_sal[i];
    const int x0 = blockIdx.x * 256;
    for (int r = 0; r < RPB; r++) {
        const int y = blockIdx.y * RPB + r;
        __syncthreads();
        for (int t = threadIdx.x; t < 265; t += 256) {
            int v = x0 - 5 + t;
            v = v < 0 ? -v : (v >= WDIM ? 2 * WDIM - 2 - v : v);  // reflect-101
            sv[t] = lut[linmap[(size_t)y * WDIM + v]];
        }
        __syncthreads();
        float s = 0.f;
#pragma unroll
        for (int k = 0; k < 10; k++) s += sv[threadIdx.x + k];
        temp[(size_t)y * WDIM + x0 + threadIdx.x] = (_Float16)s;
    }
}

// ---------------- pass E: vertical 10-tap sliding sum + scale ----------------
#define YB 64
__global__ void __launch_bounds__(256) vblur_kernel(const _Float16* __restrict__ temp,
                                                    float* __restrict__ out) {
    const int x = blockIdx.x * 256 + threadIdx.x;
    const int y0 = blockIdx.y * YB;
    float s = 0.f;
#pragma unroll
    for (int u = y0 - 5; u < y0 + 5; u++) {
        int ur = u < 0 ? -u : (u >= HDIM ? 2 * HDIM - 2 - u : u);
        s += (float)temp[(size_t)ur * WDIM + x];
    }
    for (int yy = y0; yy < y0 + YB; yy++) {
        out[(size_t)yy * WDIM + x] = s * (1.f / 100.f) * (1.f / 255.f);
        int ua = yy + 5, ub = yy - 5;
        int ura = ua >= HDIM ? 2 * HDIM - 2 - ua : ua;
        int urb = ub < 0 ? -ub : ub;
        s += (float)temp[(size_t)ura * WDIM + x] - (float)temp[(size_t)urb * WDIM + x];
    }
}

extern "C" void kernel_launch(void* const* d_in, const int* in_sizes, int n_in,
                              void* d_out, int out_size, void* d_ws, size_t ws_size,
                              hipStream_t stream) {
    const float* img = (const float*)d_in[0];
    float* out = (float*)d_out;
    char* ws = (char*)d_ws;
    // ws layout: lab planes (3*HWN bytes) | linmap u16 (2*HWN) | temp fp16 (2*HWN) |
    //            g64 (5*512*8) | minmax (24) | norm_sal (2048)
    uint8_t* lab = (uint8_t*)ws;
    uint16_t* linmap = (uint16_t*)(ws + (size_t)3 * HWN);
    _Float16* temp = (_Float16*)(ws + (size_t)5 * HWN);
    u64* g64 = (u64*)(ws + (size_t)7 * HWN);
    int* minmax = (int*)(ws + (size_t)7 * HWN + 20480);
    float* norm_sal = (float*)(ws + (size_t)7 * HWN + 20480 + 256);

    init_kernel<<<1, 256, 0, stream>>>(g64, minmax);
    lab_kernel<<<2048, 256, 0, stream>>>(img, lab, minmax);
    quant_kernel<<<1024, 256, 0, stream>>>(lab, minmax, linmap, g64);
    binproc_kernel<<<1, 512, 0, stream>>>(g64, minmax, norm_sal);
    hblur_kernel<<<dim3(WDIM / 256, HDIM / RPB), 256, 0, stream>>>(linmap, norm_sal, temp);
    vblur_kernel<<<dim3(WDIM / 256, HDIM / YB), 256, 0, stream>>>(temp, out);
}

// Round 8
// 203.647 us; speedup vs baseline: 3.2845x; 1.3518x over previous
//
#include <hip/hip_runtime.h>
#include <stdint.h>

#define HDIM 4096
#define WDIM 4096
#define HWN (HDIM*WDIM)
#define NBIN 512

typedef unsigned long long u64;

// ---------------- init: zero integer binstats, init int minmax ----------------
__global__ void init_kernel(u64* __restrict__ g64, int* __restrict__ minmax) {
    int t = threadIdx.x;
    for (int i = t; i < 5 * NBIN; i += 256) g64[i] = 0ull;
    if (t < 3) { minmax[t] = 255; minmax[3 + t] = 0; }
}

// ---------------- pass A: img f32 -> lab byte planes + integer min/max ----------------
__global__ void __launch_bounds__(256) lab_kernel(const float* __restrict__ img,
                                                  uint8_t* __restrict__ lab,
                                                  int* __restrict__ minmax) {
    const int n4 = HWN / 4;
    int mn0 = 255, mn1 = 255, mn2 = 255, mx0 = 0, mx1 = 0, mx2 = 0;
    for (int i = blockIdx.x * 256 + threadIdx.x; i < n4; i += 256 * gridDim.x) {
#pragma unroll
        for (int c = 0; c < 3; c++) {
            float4 v = ((const float4*)(img + (size_t)c * HWN))[i];
            int b0 = (int)floorf(v.x * 255.f); b0 = b0 < 0 ? 0 : (b0 > 255 ? 255 : b0);
            int b1 = (int)floorf(v.y * 255.f); b1 = b1 < 0 ? 0 : (b1 > 255 ? 255 : b1);
            int b2 = (int)floorf(v.z * 255.f); b2 = b2 < 0 ? 0 : (b2 > 255 ? 255 : b2);
            int b3 = (int)floorf(v.w * 255.f); b3 = b3 < 0 ? 0 : (b3 > 255 ? 255 : b3);
            ((unsigned*)(lab + (size_t)c * HWN))[i] =
                (unsigned)b0 | ((unsigned)b1 << 8) | ((unsigned)b2 << 16) | ((unsigned)b3 << 24);
            int lmn = min(min(b0, b1), min(b2, b3));
            int lmx = max(max(b0, b1), max(b2, b3));
            if (c == 0) { mn0 = min(mn0, lmn); mx0 = max(mx0, lmx); }
            else if (c == 1) { mn1 = min(mn1, lmn); mx1 = max(mx1, lmx); }
            else { mn2 = min(mn2, lmn); mx2 = max(mx2, lmx); }
        }
    }
#pragma unroll
    for (int off = 32; off > 0; off >>= 1) {
        mn0 = min(mn0, __shfl_down(mn0, off)); mx0 = max(mx0, __shfl_down(mx0, off));
        mn1 = min(mn1, __shfl_down(mn1, off)); mx1 = max(mx1, __shfl_down(mx1, off));
        mn2 = min(mn2, __shfl_down(mn2, off)); mx2 = max(mx2, __shfl_down(mx2, off));
    }
    __shared__ int smn[3][4], smx[3][4];
    int lane = threadIdx.x & 63, wid = threadIdx.x >> 6;
    if (lane == 0) {
        smn[0][wid] = mn0; smx[0][wid] = mx0;
        smn[1][wid] = mn1; smx[1][wid] = mx1;
        smn[2][wid] = mn2; smx[2][wid] = mx2;
    }
    __syncthreads();
    if (threadIdx.x < 3) {
        int c = threadIdx.x;
        int a = min(min(smn[c][0], smn[c][1]), min(smn[c][2], smn[c][3]));
        int z = max(max(smx[c][0], smx[c][1]), max(smx[c][2], smx[c][3]));
        atomicMin(&minmax[c], a);
        atomicMax(&minmax[3 + c], z);
    }
}

// ---------------- pass B: quantize bytes, write bin map, packed-u64 scatter stats ----------------
__global__ void __launch_bounds__(256) quant_kernel(const uint8_t* __restrict__ lab,
                                                    const int* __restrict__ minmax,
                                                    uint16_t* __restrict__ linmap,
                                                    u64* __restrict__ g64) {
    __shared__ uint8_t qlut[3 * 256];
    __shared__ u64 sA[NBIN], sB[NBIN];
    for (int i = threadIdx.x; i < NBIN; i += 256) { sA[i] = 0ull; sB[i] = 0ull; }
    for (int i = threadIdx.x; i < 3 * 256; i += 256) {
        int c = i >> 8, t = i & 255;
        float cmn = (float)minmax[c];
        float cmx = (float)minmax[3 + c];
        float step = fmaxf((cmx - cmn) / 8.f, 1e-12f);
        float q = floorf(((float)t - cmn) / step);
        int qi = (int)q;
        qi = qi < 0 ? 0 : (qi > 7 ? 7 : qi);
        qlut[i] = (uint8_t)qi;
    }
    __syncthreads();
    const uint4* p0 = (const uint4*)lab;
    const uint4* p1 = (const uint4*)(lab + (size_t)HWN);
    const uint4* p2 = (const uint4*)(lab + (size_t)2 * HWN);
    const int n16 = HWN / 16;
    for (int i = blockIdx.x * 256 + threadIdx.x; i < n16; i += 256 * gridDim.x) {
        uint4 A = p0[i], B = p1[i], C = p2[i];
        unsigned wa[4] = {A.x, A.y, A.z, A.w};
        unsigned wb[4] = {B.x, B.y, B.z, B.w};
        unsigned wc[4] = {C.x, C.y, C.z, C.w};
        int p = i * 16;
        int y = p >> 12;
        int xb = p & (WDIM - 1);
        u64 Abase = (1ull << 52) | (u64)(unsigned)y;
        u64 Bbase = (u64)(unsigned)(y * y);
        unsigned short bins[16];
#pragma unroll
        for (int w = 0; w < 4; w++) {
#pragma unroll
            for (int k = 0; k < 4; k++) {
                int l0 = (wa[w] >> (8 * k)) & 255;
                int l1 = (wb[w] >> (8 * k)) & 255;
                int l2 = (wc[w] >> (8 * k)) & 255;
                int bin = (qlut[l0] << 6) | (qlut[256 + l1] << 3) | qlut[512 + l2];
                bins[w * 4 + k] = (unsigned short)bin;
                int x = xb + w * 4 + k;
                atomicAdd(&sA[bin], Abase | ((u64)(unsigned)x << 26));
                atomicAdd(&sB[bin], ((u64)(unsigned)(x * x) << 32) | Bbase);
            }
        }
        uint4 o0, o1;
        o0.x = (unsigned)bins[0] | ((unsigned)bins[1] << 16);
        o0.y = (unsigned)bins[2] | ((unsigned)bins[3] << 16);
        o0.z = (unsigned)bins[4] | ((unsigned)bins[5] << 16);
        o0.w = (unsigned)bins[6] | ((unsigned)bins[7] << 16);
        o1.x = (unsigned)bins[8] | ((unsigned)bins[9] << 16);
        o1.y = (unsigned)bins[10] | ((unsigned)bins[11] << 16);
        o1.z = (unsigned)bins[12] | ((unsigned)bins[13] << 16);
        o1.w = (unsigned)bins[14] | ((unsigned)bins[15] << 16);
        ((uint4*)linmap)[i * 2] = o0;
        ((uint4*)linmap)[i * 2 + 1] = o1;
    }
    __syncthreads();
    for (int i = threadIdx.x; i < NBIN; i += 256) {
        u64 A = sA[i];
        if (A) {
            u64 B = sB[i];
            atomicAdd(&g64[i],            A >> 52);
            atomicAdd(&g64[NBIN + i],     (A >> 26) & 0x3FFFFFFull);
            atomicAdd(&g64[2 * NBIN + i], A & 0x3FFFFFFull);
            atomicAdd(&g64[3 * NBIN + i], B >> 32);
            atomicAdd(&g64[4 * NBIN + i], B & 0xFFFFFFFFull);
        }
    }
}

// ------- helper: compute bin-edge tables into LDS (24 threads) -------
__device__ inline void load_edges(const int* minmax, float* e0, float* e1, float* e2, int tid) {
    if (tid < 24) {
        int c = tid >> 3, k = tid & 7;
        float cmn = (float)minmax[c];
        float cmx = (float)minmax[3 + c];
        float step = fmaxf((cmx - cmn) / 8.f, 1e-12f);
        float e = cmn + (float)k * step;
        if (c == 0) e0[k] = e; else if (c == 1) e1[k] = e; else e2[k] = e;
    }
}

// ---------------- pass C1: bilateral matvecs + shape prob -> salm, maskf ----------------
// grid 8 blocks x 512 thr; block b owns bins [64b,64b+64); thread = jc*64 + binLocal
__global__ void __launch_bounds__(512) binstat1_kernel(const u64* __restrict__ g64,
                                                       const int* __restrict__ minmax,
                                                       float* __restrict__ salm,
                                                       float* __restrict__ maskf) {
    __shared__ float sh[NBIN], sx[NBIN], sy[NBIN], sx2[NBIN], sy2[NBIN];
    __shared__ float e0[8], e1[8], e2[8];
    __shared__ float parts[6][8][64];
    const int tid = threadIdx.x;
    const int bl = tid & 63, jc = tid >> 6;
    if (tid < NBIN) {
        sh[tid]  = (float)g64[tid];
        sx[tid]  = (float)g64[NBIN + tid];
        sy[tid]  = (float)g64[2 * NBIN + tid];
        sx2[tid] = (float)g64[3 * NBIN + tid];
        sy2[tid] = (float)g64[4 * NBIN + tid];
    }
    load_edges(minmax, e0, e1, e2, tid);
    __syncthreads();
    const int bin = blockIdx.x * 64 + bl;
    const float c0 = e0[bin >> 6], c1 = e1[(bin >> 3) & 7], c2 = e2[bin & 7];
    float contrast = 0.f, en = 0.f, ex = 0.f, ey = 0.f, ex2 = 0.f, ey2 = 0.f;
    for (int j = jc * 64; j < jc * 64 + 64; j++) {
        float d0 = c0 - e0[j >> 6], d1 = c1 - e1[(j >> 3) & 7], d2c = c2 - e2[j & 7];
        float d2 = d0 * d0 + d1 * d1 + d2c * d2c;
        float D = sqrtf(d2);
        float E = __expf(-d2 * (1.f / 512.f));
        float h = sh[j];
        contrast += D * h; en += E * h;
        ex += E * sx[j]; ey += E * sy[j]; ex2 += E * sx2[j]; ey2 += E * sy2[j];
    }
    parts[0][jc][bl] = contrast; parts[1][jc][bl] = en;
    parts[2][jc][bl] = ex;       parts[3][jc][bl] = ey;
    parts[4][jc][bl] = ex2;      parts[5][jc][bl] = ey2;
    __syncthreads();
    if (jc == 0) {
        contrast = 0.f; en = 0.f; ex = 0.f; ey = 0.f; ex2 = 0.f; ey2 = 0.f;
        for (int w = 0; w < 8; w++) {
            contrast += parts[0][w][bl]; en  += parts[1][w][bl];
            ex       += parts[2][w][bl]; ey  += parts[3][w][bl];
            ex2      += parts[4][w][bl]; ey2 += parts[5][w][bl];
        }
        float norm = fmaxf(en, 1e-8f);
        float mx = ex / norm, my = ey / norm, mx2 = ex2 / norm, my2 = ey2 / norm;
        float vx = fmaxf(mx2 - mx * mx, 0.f), vy = fmaxf(my2 - my * my, 0.f);
        float g0 = sqrtf(12.f * vx) / 4096.f;
        float g1 = sqrtf(12.f * vy) / 4096.f;
        float g2 = (mx - 2048.f) / 4096.f;
        float g3 = (my - 2048.f) / 4096.f;
        const float CI[4][4] = {{43.3777f, 1.7633f, -0.4059f, 1.0997f},
                                {1.7633f, 40.7221f, -0.0165f, 0.0447f},
                                {-0.4059f, -0.0165f, 87.0455f, -3.2744f},
                                {1.0997f, 0.0447f, -3.2744f, 125.1503f}};
        float xc[4] = {g0 - 0.5555f, g1 - 0.6449f, g2 - 0.0002f, g3 - 0.0063f};
        float maha = 0.f;
#pragma unroll
        for (int ii = 0; ii < 4; ii++)
#pragma unroll
            for (int jj = 0; jj < 4; jj++) maha += xc[ii] * CI[ii][jj] * xc[jj];
        float sp = __expf(-0.5f * maha);
        float mf = sh[bin] > 0.f ? 1.f : 0.f;
        salm[bin] = contrast * sp * mf;
        maskf[bin] = mf;
    }
}

// ---------------- pass C2: smoothing matvec -> smoothed ----------------
__global__ void __launch_bounds__(512) binstat2_kernel(const float* __restrict__ salm,
                                                       const float* __restrict__ maskf,
                                                       const int* __restrict__ minmax,
                                                       float* __restrict__ smoothed) {
    __shared__ float ssal[NBIN], smsk[NBIN];
    __shared__ float e0[8], e1[8], e2[8];
    __shared__ float parts[2][8][64];
    const int tid = threadIdx.x;
    const int bl = tid & 63, jc = tid >> 6;
    if (tid < NBIN) { ssal[tid] = salm[tid]; smsk[tid] = maskf[tid]; }
    load_edges(minmax, e0, e1, e2, tid);
    __syncthreads();
    const int bin = blockIdx.x * 64 + bl;
    const float c0 = e0[bin >> 6], c1 = e1[(bin >> 3) & 7], c2 = e2[bin & 7];
    float num = 0.f, den = 0.f;
    for (int j = jc * 64; j < jc * 64 + 64; j++) {
        float d0 = c0 - e0[j >> 6], d1 = c1 - e1[(j >> 3) & 7], d2c = c2 - e2[j & 7];
        float d2 = d0 * d0 + d1 * d1 + d2c * d2c;
        float E = __expf(-d2 * (1.f / 512.f));
        num += E * ssal[j]; den += E * smsk[j];
    }
    parts[0][jc][bl] = num; parts[1][jc][bl] = den;
    __syncthreads();
    if (jc == 0) {
        num = 0.f; den = 0.f;
        for (int w = 0; w < 8; w++) { num += parts[0][w][bl]; den += parts[1][w][bl]; }
        smoothed[bin] = num / fmaxf(den, 1e-8f);
    }
}

// ---------------- pass C3: min/max over occupied bins -> norm_sal ----------------
__global__ void __launch_bounds__(512) norm_kernel(const float* __restrict__ smoothed,
                                                   const float* __restrict__ maskf,
                                                   float* __restrict__ norm_sal) {
    __shared__ float rmn[8], rmx[8];
    const int b = threadIdx.x;
    float sm = smoothed[b];
    float mf = maskf[b];
    float vmn = mf > 0.f ? sm : INFINITY;
    float vmx = mf > 0.f ? sm : -INFINITY;
#pragma unroll
    for (int off = 32; off > 0; off >>= 1) {
        vmn = fminf(vmn, __shfl_down(vmn, off));
        vmx = fmaxf(vmx, __shfl_down(vmx, off));
    }
    int lane = b & 63, wid = b >> 6;
    if (lane == 0) { rmn[wid] = vmn; rmx[wid] = vmx; }
    __syncthreads();
    if (b == 0) {
        float a = rmn[0], z = rmx[0];
        for (int w = 1; w < 8; w++) { a = fminf(a, rmn[w]); z = fmaxf(z, rmx[w]); }
        rmn[0] = a; rmx[0] = z;
    }
    __syncthreads();
    float mnv = rmn[0], mxv = rmx[0];
    float ns = (mxv > mnv) ? 255.f * (sm - mnv) / fmaxf(mxv - mnv, 1e-30f) : 0.f;
    norm_sal[b] = ns;
}

// ---------------- pass D: gather + horizontal 10-tap sum (fp16 temp) ----------------
#define RPB 4
__global__ void __launch_bounds__(256) hblur_kernel(const uint16_t* __restrict__ linmap,
                                                    const float* __restrict__ norm_sal,
                                                    _Float16* __restrict__ temp) {
    __shared__ float lut[NBIN];
    __shared__ float sv[256 + 9];
    for (int i = threadIdx.x; i < NBIN; i += 256) lut[i] = norm_sal[i];
    const int x0 = blockIdx.x * 256;
    for (int r = 0; r < RPB; r++) {
        const int y = blockIdx.y * RPB + r;
        __syncthreads();
        for (int t = threadIdx.x; t < 265; t += 256) {
            int v = x0 - 5 + t;
            v = v < 0 ? -v : (v >= WDIM ? 2 * WDIM - 2 - v : v);  // reflect-101
            sv[t] = lut[linmap[(size_t)y * WDIM + v]];
        }
        __syncthreads();
        float s = 0.f;
#pragma unroll
        for (int k = 0; k < 10; k++) s += sv[threadIdx.x + k];
        temp[(size_t)y * WDIM + x0 + threadIdx.x] = (_Float16)s;
    }
}

// ---------------- pass E: vertical 10-tap sliding sum + scale ----------------
#define YB 128
__global__ void __launch_bounds__(256) vblur_kernel(const _Float16* __restrict__ temp,
                                                    float* __restrict__ out) {
    const int x = blockIdx.x * 256 + threadIdx.x;
    const int y0 = blockIdx.y * YB;
    float s = 0.f;
#pragma unroll
    for (int u = y0 - 5; u < y0 + 5; u++) {
        int ur = u < 0 ? -u : (u >= HDIM ? 2 * HDIM - 2 - u : u);
        s += (float)temp[(size_t)ur * WDIM + x];
    }
    for (int yy = y0; yy < y0 + YB; yy++) {
        out[(size_t)yy * WDIM + x] = s * (1.f / 100.f) * (1.f / 255.f);
        int ua = yy + 5, ub = yy - 5;
        int ura = ua >= HDIM ? 2 * HDIM - 2 - ua : ua;
        int urb = ub < 0 ? -ub : ub;
        s += (float)temp[(size_t)ura * WDIM + x] - (float)temp[(size_t)urb * WDIM + x];
    }
}

extern "C" void kernel_launch(void* const* d_in, const int* in_sizes, int n_in,
                              void* d_out, int out_size, void* d_ws, size_t ws_size,
                              hipStream_t stream) {
    const float* img = (const float*)d_in[0];
    float* out = (float*)d_out;
    char* ws = (char*)d_ws;
    // ws: lab (3*HWN) | linmap u16 (2*HWN) | temp fp16 (2*HWN) | g64 (5*512*8) |
    //     minmax (24B pad 32) | salm | maskf | smoothed | norm_sal (512 f32 each)
    uint8_t* lab = (uint8_t*)ws;
    uint16_t* linmap = (uint16_t*)(ws + (size_t)3 * HWN);
    _Float16* temp = (_Float16*)(ws + (size_t)5 * HWN);
    u64* g64 = (u64*)(ws + (size_t)7 * HWN);
    char* tail = ws + (size_t)7 * HWN + 20480;
    int* minmax = (int*)tail;
    float* salm = (float*)(tail + 32);
    float* maskf = (float*)(tail + 32 + 2048);
    float* smoothed = (float*)(tail + 32 + 4096);
    float* norm_sal = (float*)(tail + 32 + 6144);

    init_kernel<<<1, 256, 0, stream>>>(g64, minmax);
    lab_kernel<<<2048, 256, 0, stream>>>(img, lab, minmax);
    quant_kernel<<<1024, 256, 0, stream>>>(lab, minmax, linmap, g64);
    binstat1_kernel<<<8, 512, 0, stream>>>(g64, minmax, salm, maskf);
    binstat2_kernel<<<8, 512, 0, stream>>>(salm, maskf, minmax, smoothed);
    norm_kernel<<<1, 512, 0, stream>>>(smoothed, maskf, norm_sal);
    hblur_kernel<<<dim3(WDIM / 256, HDIM / RPB), 256, 0, stream>>>(linmap, norm_sal, temp);
    vblur_kernel<<<dim3(WDIM / 256, HDIM / YB), 256, 0, stream>>>(temp, out);
}